// Round 6
// baseline (1122.656 us; speedup 1.0000x reference)
//
#include <hip/hip_runtime.h>
#include <math.h>

#define NB 16
#define NH 64
#define NPTS 2048
#define NEIGHS 20
#define KSEL 512
#define EPSV 1e-5f
#define NINF -3.0e38f

// output layout (floats), reference return order
#define OFF_SEQ 0
#define OFF_VAL (NB*NH*KSEL)            // 524288
#define OFF_IDX (OFF_VAL + NB*KSEL)     // 532480
#define OFF_RET (OFF_IDX + NB*KSEL)     // 540672
#define OFF_XST (OFF_RET + NB*2*NPTS)   // 606208
#define OFF_XO  (OFF_XST + NB*3*KSEL)   // 630784

__device__ __forceinline__ bool better(float av, int ai, float bv, int bi) {
  return (av > bv) || (av == bv && ai < bi);
}

// K1: pts = relu(bn1(Wfc@seq1 + bfc)), plus x2, G1, G2, and ptsT [b][c][n].
// 4 waves per 64-point block; each wave computes a disjoint 16-wide o-range
// with the EXACT per-o fmaf chain of the passing R2/R4 kernel (bitwise).
__global__ __launch_bounds__(256) void k_fc(const float* __restrict__ seq1,
                                            const float* __restrict__ Wfc,
                                            const float* __restrict__ bfc,
                                            const float* __restrict__ b1g,
                                            const float* __restrict__ b1b,
                                            const float* __restrict__ b1m,
                                            const float* __restrict__ b1v,
                                            const float* __restrict__ Wec,
                                            float* __restrict__ pts,
                                            float* __restrict__ ptsT,
                                            float* __restrict__ G1,
                                            float* __restrict__ G2,
                                            float* __restrict__ x2) {
  const int b = blockIdx.y, n0 = blockIdx.x * 64;
  const int tid = threadIdx.x, l = tid & 63, w = tid >> 6;
  const int n = n0 + l;
  __shared__ float ptL[64*65];
  const float* sq = seq1 + (size_t)b*NH*NPTS + n;
  float x[64];
  #pragma unroll
  for (int c = 0; c < 64; ++c) x[c] = sq[(size_t)c*NPTS];

  // phase 1: fc + bn1 + relu (o split across waves; exact chain per o)
  for (int oo = 0; oo < 16; ++oo) {
    const int o = w*16 + oo;
    float acc = 0.f;
    const float* ar = Wfc + o*64;
    #pragma unroll
    for (int c = 0; c < 64; c += 4) {
      float4 a4 = *(const float4*)(ar + c);
      acc = fmaf(a4.x, x[c],   acc);
      acc = fmaf(a4.y, x[c+1], acc);
      acc = fmaf(a4.z, x[c+2], acc);
      acc = fmaf(a4.w, x[c+3], acc);
    }
    float s1 = b1g[o] / sqrtf(b1v[o] + EPSV);
    float y  = (acc + bfc[o] - b1m[o]) * s1 + b1b[o];
    ptL[l*65 + o] = fmaxf(y, 0.f);
  }
  __syncthreads();
  float pt[64];
  #pragma unroll
  for (int c = 0; c < 64; ++c) pt[c] = ptL[l*65 + c];
  if (w == 0) {
    float s2 = 0.f;
    #pragma unroll
    for (int c = 0; c < 64; ++c) s2 = fmaf(pt[c], pt[c], s2);
    x2[(size_t)b*NPTS + n] = s2;
  }
  const size_t base = ((size_t)b*NPTS + n0)*NH;
  // coalesced flush of pts + ptsT (wave-split ranges)
  for (int t = w*16; t < w*16 + 16; ++t) pts[base + t*64 + l] = ptL[t*65 + l];
  for (int c = w*16; c < w*16 + 16; ++c)
    ptsT[((size_t)b*NH + c)*NPTS + n] = ptL[l*65 + c];
  __syncthreads();

  // phase 2a: G1 = pts . Wec[:, :64]^T (exact chain per o)
  for (int oo = 0; oo < 16; ++oo) {
    const int o = w*16 + oo;
    const float* w1 = Wec + o*128;
    float a1 = 0.f;
    #pragma unroll
    for (int c = 0; c < 64; c += 4) {
      float4 u = *(const float4*)(w1 + c);
      a1 = fmaf(u.x, pt[c],   a1); a1 = fmaf(u.y, pt[c+1], a1);
      a1 = fmaf(u.z, pt[c+2], a1); a1 = fmaf(u.w, pt[c+3], a1);
    }
    ptL[l*65 + o] = a1;
  }
  __syncthreads();
  for (int t = w*16; t < w*16 + 16; ++t) G1[base + t*64 + l] = ptL[t*65 + l];
  __syncthreads();

  // phase 2b: G2 = pts . Wec[:, 64:]^T (exact chain per o)
  for (int oo = 0; oo < 16; ++oo) {
    const int o = w*16 + oo;
    const float* w2 = Wec + o*128 + 64;
    float a2 = 0.f;
    #pragma unroll
    for (int c = 0; c < 64; c += 4) {
      float4 v = *(const float4*)(w2 + c);
      a2 = fmaf(v.x, pt[c],   a2); a2 = fmaf(v.y, pt[c+1], a2);
      a2 = fmaf(v.z, pt[c+2], a2); a2 = fmaf(v.w, pt[c+3], a2);
    }
    ptL[l*65 + o] = a2;
  }
  __syncthreads();
  for (int t = w*16; t < w*16 + 16; ++t) G2[base + t*64 + l] = ptL[t*65 + l];
}

// K2: lane-owns-row kNN. Block = 4 waves x 4 rows = 16 rows, all 2048 cols.
// NOTE: __launch_bounds__(256) with NO min-waves arg — this kernel needs
// ~200 VGPRs (128 accumulators); capping at 128 (R5's ",2") spilled ~2 GB
// to scratch per dispatch. 1 wave/SIMD is fine: 32 independent acc chains
// give ILP, and the per-CU LDS pipe load (~83 us total) < FMA time.
__global__ __launch_bounds__(256) void k_knn(const float* __restrict__ pts,
                                             const float* __restrict__ ptsT,
                                             const float* __restrict__ x2,
                                             int* __restrict__ nidx) {
  const int lin = blockIdx.x;
  const int b  = ((lin & 7) << 1) | ((lin >> 3) & 1);  // XCD-local batches
  const int rg = lin >> 4;                              // 0..127
  const int tid = threadIdx.x, w = tid >> 6, l = tid & 63;
  const int r0 = rg*16 + w*4;

  __shared__ float colB[2][4*NPTS];   // 2 x 32 KB

  const float* Tb = ptsT + (size_t)b*NH*NPTS;
  const float* prow = pts + ((size_t)b*NPTS + r0)*NH;

  float a0[32], a1[32], a2[32], a3[32];
  #pragma unroll
  for (int j = 0; j < 32; ++j) { a0[j]=0.f; a1[j]=0.f; a2[j]=0.f; a3[j]=0.f; }

  { // prologue: stage chunk 0
    float4 st[8];
    #pragma unroll
    for (int s = 0; s < 8; ++s) st[s] = *(const float4*)(Tb + s*1024 + tid*4);
    #pragma unroll
    for (int s = 0; s < 8; ++s) *(float4*)(&colB[0][s*1024 + tid*4]) = st[s];
  }
  __syncthreads();

  #pragma unroll 1
  for (int t = 0; t < 16; ++t) {
    float4 nx[8];
    if (t < 15) { // issue next chunk's loads early (hide under FMA)
      const float* src = Tb + (size_t)(t+1)*8192;
      #pragma unroll
      for (int s = 0; s < 8; ++s) nx[s] = *(const float4*)(src + s*1024 + tid*4);
    }
    float4 rv0 = *(const float4*)(prow + 0*NH + t*4);
    float4 rv1 = *(const float4*)(prow + 1*NH + t*4);
    float4 rv2 = *(const float4*)(prow + 2*NH + t*4);
    float4 rv3 = *(const float4*)(prow + 3*NH + t*4);
    const float* cb = &colB[t & 1][0];
    #pragma unroll
    for (int k = 0; k < 4; ++k) {
      float4 f[8];
      #pragma unroll
      for (int jj = 0; jj < 8; ++jj)
        f[jj] = *(const float4*)(cb + k*NPTS + jj*256 + l*4);
      const float r0k = (k==0)?rv0.x:(k==1)?rv0.y:(k==2)?rv0.z:rv0.w;
      const float r1k = (k==0)?rv1.x:(k==1)?rv1.y:(k==2)?rv1.z:rv1.w;
      const float r2k = (k==0)?rv2.x:(k==1)?rv2.y:(k==2)?rv2.z:rv2.w;
      const float r3k = (k==0)?rv3.x:(k==1)?rv3.y:(k==2)?rv3.z:rv3.w;
      #pragma unroll
      for (int jj = 0; jj < 8; ++jj) {
        a0[jj*4+0] = fmaf(r0k, f[jj].x, a0[jj*4+0]);
        a0[jj*4+1] = fmaf(r0k, f[jj].y, a0[jj*4+1]);
        a0[jj*4+2] = fmaf(r0k, f[jj].z, a0[jj*4+2]);
        a0[jj*4+3] = fmaf(r0k, f[jj].w, a0[jj*4+3]);
        a1[jj*4+0] = fmaf(r1k, f[jj].x, a1[jj*4+0]);
        a1[jj*4+1] = fmaf(r1k, f[jj].y, a1[jj*4+1]);
        a1[jj*4+2] = fmaf(r1k, f[jj].z, a1[jj*4+2]);
        a1[jj*4+3] = fmaf(r1k, f[jj].w, a1[jj*4+3]);
        a2[jj*4+0] = fmaf(r2k, f[jj].x, a2[jj*4+0]);
        a2[jj*4+1] = fmaf(r2k, f[jj].y, a2[jj*4+1]);
        a2[jj*4+2] = fmaf(r2k, f[jj].z, a2[jj*4+2]);
        a2[jj*4+3] = fmaf(r2k, f[jj].w, a2[jj*4+3]);
        a3[jj*4+0] = fmaf(r3k, f[jj].x, a3[jj*4+0]);
        a3[jj*4+1] = fmaf(r3k, f[jj].y, a3[jj*4+1]);
        a3[jj*4+2] = fmaf(r3k, f[jj].z, a3[jj*4+2]);
        a3[jj*4+3] = fmaf(r3k, f[jj].w, a3[jj*4+3]);
      }
    }
    if (t < 15) { // write staged regs to the other buffer
      #pragma unroll
      for (int s = 0; s < 8; ++s)
        *(float4*)(&colB[(t+1)&1][s*1024 + tid*4]) = nx[s];
    }
    __syncthreads();
  }

  // selection: key = 2*dot - x2[col] (row term rank-invariant; same as R4)
  float x2v[32];
  #pragma unroll
  for (int jj = 0; jj < 8; ++jj)
    *(float4*)(&x2v[jj*4]) = *(const float4*)(x2 + (size_t)b*NPTS + jj*256 + l*4);

  #pragma unroll 1
  for (int r = 0; r < 4; ++r) {
    float tmp[32];
    #pragma unroll
    for (int j = 0; j < 32; ++j)
      tmp[j] = (r == 0) ? a0[j] : (r == 1) ? a1[j] : (r == 2) ? a2[j] : a3[j];

    // per-lane sorted-4 build; stream (j asc) is col-asc so strict '>'
    // preserves the idx-asc tie-break; (bv,bi) = best element ever discarded
    float L0v=NINF,L1v=NINF,L2v=NINF,L3v=NINF;
    int   L0i=0x7fffffff,L1i=0x7fffffff,L2i=0x7fffffff,L3i=0x7fffffff;
    float bv = NINF; int bi = 0x7fffffff;
    #pragma unroll
    for (int j = 0; j < 32; ++j) {
      float cv = fmaf(2.0f, tmp[j], -x2v[j]);
      int   ci = ((j >> 2) << 8) + (j & 3) + (l << 2);
      { bool c = cv > L0v; float nv=c?cv:L0v; int ni=c?ci:L0i; float ov=L0v; int oi=L0i; cv=c?ov:cv; ci=c?oi:ci; L0v=nv; L0i=ni; }
      { bool c = cv > L1v; float nv=c?cv:L1v; int ni=c?ci:L1i; float ov=L1v; int oi=L1i; cv=c?ov:cv; ci=c?oi:ci; L1v=nv; L1i=ni; }
      { bool c = cv > L2v; float nv=c?cv:L2v; int ni=c?ci:L2i; float ov=L2v; int oi=L2i; cv=c?ov:cv; ci=c?oi:ci; L2v=nv; L2i=ni; }
      { bool c = cv > L3v; float nv=c?cv:L3v; int ni=c?ci:L3i; float ov=L3v; int oi=L3i; cv=c?ov:cv; ci=c?oi:ci; L3v=nv; L3i=ni; }
      bool bb = better(cv, ci, bv, bi);
      bv = bb ? cv : bv; bi = bb ? ci : bi;
    }

    // 20x wave-argmax extraction
    float h0=L0v,h1=L1v,h2=L2v,h3=L3v;
    int   e0=L0i,e1=L1i,e2=L2i,e3=L3i;
    int myNb = 0;
    float lastv = NINF; int lasti = 0x7fffffff;
    #pragma unroll 1
    for (int t20 = 0; t20 < NEIGHS; ++t20) {
      float gv = h0; int gi = e0;
      #pragma unroll
      for (int m = 32; m >= 1; m >>= 1) {
        float ov = __shfl_xor(gv, m, 64);
        int   oi = __shfl_xor(gi, m, 64);
        bool bt = better(ov, oi, gv, gi);
        gv = bt ? ov : gv; gi = bt ? oi : gi;
      }
      bool win = (h0 == gv) && (e0 == gi);
      h0 = win ? h1 : h0; e0 = win ? e1 : e0;
      h1 = win ? h2 : h1; e1 = win ? e2 : e1;
      h2 = win ? h3 : h2; e2 = win ? e3 : e2;
      h3 = win ? NINF : h3; e3 = win ? 0x7fffffff : e3;
      if (l == t20) myNb = gi;
      lastv = gv; lasti = gi;
    }
    // airtight check: if any lane's best-discarded beats the 20th pick,
    // re-extract this row exactly from the full streams (rare)
    bool flag = better(bv, bi, lastv, lasti);
    if (__any((int)flag)) {
      unsigned taken = 0u;
      #pragma unroll 1
      for (int t20 = 0; t20 < NEIGHS; ++t20) {
        float pv = NINF; int pi = 0x7fffffff; int pj = 0;
        #pragma unroll
        for (int j = 0; j < 32; ++j) {
          float kv = fmaf(2.0f, tmp[j], -x2v[j]);
          int   ci = ((j >> 2) << 8) + (j & 3) + (l << 2);
          bool av2 = ((taken >> j) & 1u) == 0u;
          bool bt = av2 && better(kv, ci, pv, pi);
          pv = bt ? kv : pv; pi = bt ? ci : pi; pj = bt ? j : pj;
        }
        float gv = pv; int gi = pi;
        #pragma unroll
        for (int m = 32; m >= 1; m >>= 1) {
          float ov = __shfl_xor(gv, m, 64);
          int   oi = __shfl_xor(gi, m, 64);
          bool bt = better(ov, oi, gv, gi);
          gv = bt ? ov : gv; gi = bt ? oi : gi;
        }
        if ((pv == gv) && (pi == gi)) taken |= (1u << pj);
        if (l == t20) myNb = gi;
      }
    }
    if (l < NEIGHS) nidx[((size_t)b*NPTS + r0 + r)*NEIGHS + l] = myNb;
  }
}

// K3: per-point neighbor max -> X -> v = Wb@X -> sc1/sc2/ret. One wave per point.
__global__ __launch_bounds__(256) void k_score(const float* __restrict__ pts,
    const float* __restrict__ G1, const float* __restrict__ G2,
    const int* __restrict__ nidx, const int* __restrict__ perm,
    const float* __restrict__ Wb,
    const float* __restrict__ b2g, const float* __restrict__ b2b,
    const float* __restrict__ b2m, const float* __restrict__ b2v,
    const float* __restrict__ bb,
    float* __restrict__ sc1w, float* __restrict__ out) {
  const int b = blockIdx.y;
  const int n0 = blockIdx.x * 16;
  const int tid = threadIdx.x, l = tid & 63, w = tid >> 6;
  __shared__ float WbS[64*65];
  for (int i = tid; i < 64*64; i += 256) WbS[(i >> 6)*65 + (i & 63)] = Wb[i];
  __syncthreads();
  const float sc2v = b2g[l] / sqrtf(b2v[l] + EPSV);
  const float mean2 = b2m[l], beta2 = b2b[l];
  const float bbv = bb[0];
  const float* G1b = G1 + (size_t)b*NPTS*NH;
  for (int it = 0; it < 4; ++it) {
    const int n = n0 + it*4 + w;
    const size_t ro = (size_t)b*NPTS*NH + (size_t)n*NH;
    const float base = G2[ro + l] - G1[ro + l];
    const int* nb = nidx + ((size_t)b*NPTS + n)*NEIGHS;
    float mx = NINF;
    #pragma unroll
    for (int k = 0; k < NEIGHS; ++k) {
      int m = nb[k];
      float val = G1b[(size_t)m*NH + l] + base;
      float y = (val - mean2) * sc2v + beta2;
      y = (y >= 0.f) ? y : 0.2f*y;
      mx = fmaxf(mx, y);
    }
    float X = 1.f / (1.f + expf(-mx));
    double v = 0.0;
    #pragma unroll
    for (int d = 0; d < 64; ++d) {
      float xd = __shfl(X, d, 64);
      v += (double)WbS[l*65 + d] * (double)xd;
    }
    float p1 = pts[ro + l];
    int pn = perm[n];
    float p2 = pts[(size_t)b*NPTS*NH + (size_t)pn*NH + l];
    double s1 = (double)p1 * v;
    double s2 = (double)p2 * v;
    #pragma unroll
    for (int off = 32; off > 0; off >>= 1) {
      s1 += __shfl_xor(s1, off, 64);
      s2 += __shfl_xor(s2, off, 64);
    }
    if (l == 0) {
      float r1 = (float)(s1 + (double)bbv);
      float r2 = (float)(s2 + (double)bbv);
      sc1w[(size_t)b*NPTS + n] = r1;
      out[OFF_RET + (size_t)b*2*NPTS + n] = r1;
      out[OFF_RET + (size_t)b*2*NPTS + NPTS + n] = r2;
    }
  }
}

// K4: per-batch exact top-512 (value desc, idx asc) via u64 bitonic sort + gathers
__global__ __launch_bounds__(256) void k_select(const float* __restrict__ sc1w,
    const float* __restrict__ seq1, const float* __restrict__ xyz,
    float* __restrict__ out) {
  const int b = blockIdx.x, tid = threadIdx.x;
  __shared__ unsigned long long keys[NPTS];
  __shared__ float valS[KSEL];
  __shared__ int idxS[KSEL];
  for (int i = tid; i < NPTS; i += 256) {
    float f = sc1w[(size_t)b*NPTS + i];
    unsigned u = __float_as_uint(f);
    u = (u & 0x80000000u) ? ~u : (u | 0x80000000u);
    keys[i] = ((unsigned long long)(~u) << 32) | (unsigned)i;
  }
  __syncthreads();
  for (int k = 2; k <= NPTS; k <<= 1) {
    for (int j = k >> 1; j > 0; j >>= 1) {
      for (int i = tid; i < NPTS; i += 256) {
        int l2 = i ^ j;
        if (l2 > i) {
          unsigned long long a = keys[i], c = keys[l2];
          bool up = ((i & k) == 0);
          if ((a > c) == up) { keys[i] = c; keys[l2] = a; }
        }
      }
      __syncthreads();
    }
  }
  for (int i = tid; i < KSEL; i += 256) {
    unsigned long long key = keys[i];
    int sidx = (int)(key & 0xffffffffULL);
    unsigned u = ~(unsigned)(key >> 32);
    unsigned fb = (u & 0x80000000u) ? (u & 0x7fffffffu) : ~u;
    float f = __uint_as_float(fb);
    float val = 1.f / (1.f + expf(-f));
    valS[i] = val; idxS[i] = sidx;
    out[OFF_VAL + (size_t)b*KSEL + i] = val;
    out[OFF_IDX + (size_t)b*KSEL + i] = (float)sidx;
  }
  __syncthreads();
  for (int t = tid; t < NH*KSEL; t += 256) {
    int c = t >> 9, i = t & (KSEL-1);
    float sv = seq1[((size_t)b*NH + c)*NPTS + idxS[i]];
    out[OFF_SEQ + (((size_t)b*NH + c) << 9) + i] = sv * valS[i];
  }
  for (int t = tid; t < 3*KSEL; t += 256) {
    int c = t >> 9, i = t & (KSEL-1);
    float xv = xyz[((size_t)b*3 + c)*NPTS + idxS[i]];
    out[OFF_XST + (((size_t)b*3 + c) << 9) + i] = xv;
    out[OFF_XO  + (((size_t)b*3 + c) << 9) + i] = xv * valS[i];
  }
}

extern "C" void kernel_launch(void* const* d_in, const int* in_sizes, int n_in,
                              void* d_out, int out_size, void* d_ws, size_t ws_size,
                              hipStream_t stream) {
  const float* xyz  = (const float*)d_in[0];
  const float* seq1 = (const float*)d_in[1];
  const int*   perm = (const int*)d_in[2];
  const float* Wfc  = (const float*)d_in[3];
  const float* bfc  = (const float*)d_in[4];
  const float* b1g  = (const float*)d_in[5];
  const float* b1b  = (const float*)d_in[6];
  const float* b1m  = (const float*)d_in[7];
  const float* b1v  = (const float*)d_in[8];
  const float* Wec  = (const float*)d_in[9];
  const float* b2g  = (const float*)d_in[10];
  const float* b2b  = (const float*)d_in[11];
  const float* b2m  = (const float*)d_in[12];
  const float* b2v  = (const float*)d_in[13];
  const float* Wb   = (const float*)d_in[14];
  const float* bb   = (const float*)d_in[15];
  float* out = (float*)d_out;

  float* ws   = (float*)d_ws;
  float* pts  = ws;
  float* ptsT = pts + (size_t)NB*NPTS*NH;
  float* G1   = ptsT + (size_t)NB*NPTS*NH;
  float* G2   = G1  + (size_t)NB*NPTS*NH;
  float* x2   = G2  + (size_t)NB*NPTS*NH;
  float* sc1w = x2  + (size_t)NB*NPTS;
  int*   nidx = (int*)(sc1w + (size_t)NB*NPTS);

  hipLaunchKernelGGL(k_fc, dim3(NPTS/64, NB), dim3(256), 0, stream,
                     seq1, Wfc, bfc, b1g, b1b, b1m, b1v, Wec, pts, ptsT, G1, G2, x2);
  hipLaunchKernelGGL(k_knn, dim3(NB*NPTS/16), dim3(256), 0, stream,
                     pts, ptsT, x2, nidx);
  hipLaunchKernelGGL(k_score, dim3(NPTS/16, NB), dim3(256), 0, stream,
                     pts, G1, G2, nidx, perm, Wb, b2g, b2b, b2m, b2v, bb, sc1w, out);
  hipLaunchKernelGGL(k_select, dim3(NB), dim3(256), 0, stream,
                     sc1w, seq1, xyz, out);
}

// Round 7
// 1120.210 us; speedup vs baseline: 1.0022x; 1.0022x over previous
//
#include <hip/hip_runtime.h>
#include <math.h>

#define NB 16
#define NH 64
#define NPTS 2048
#define NEIGHS 20
#define KSEL 512
#define EPSV 1e-5f
#define NINF -3.0e38f

// output layout (floats), reference return order
#define OFF_SEQ 0
#define OFF_VAL (NB*NH*KSEL)            // 524288
#define OFF_IDX (OFF_VAL + NB*KSEL)     // 532480
#define OFF_RET (OFF_IDX + NB*KSEL)     // 540672
#define OFF_XST (OFF_RET + NB*2*NPTS)   // 606208
#define OFF_XO  (OFF_XST + NB*3*KSEL)   // 630784

__device__ __forceinline__ bool better(float av, int ai, float bv, int bi) {
  return (av > bv) || (av == bv && ai < bi);
}

// K1: pts = relu(bn1(Wfc@seq1 + bfc)), plus x2, G1, G2, and ptsT [b][c][n].
// 4 waves per 64-point block; each wave computes a disjoint 16-wide o-range
// with the EXACT per-o fmaf chain of the passing R2/R4 kernel (bitwise).
__global__ __launch_bounds__(256) void k_fc(const float* __restrict__ seq1,
                                            const float* __restrict__ Wfc,
                                            const float* __restrict__ bfc,
                                            const float* __restrict__ b1g,
                                            const float* __restrict__ b1b,
                                            const float* __restrict__ b1m,
                                            const float* __restrict__ b1v,
                                            const float* __restrict__ Wec,
                                            float* __restrict__ pts,
                                            float* __restrict__ ptsT,
                                            float* __restrict__ G1,
                                            float* __restrict__ G2,
                                            float* __restrict__ x2) {
  const int b = blockIdx.y, n0 = blockIdx.x * 64;
  const int tid = threadIdx.x, l = tid & 63, w = tid >> 6;
  const int n = n0 + l;
  __shared__ float ptL[64*65];
  const float* sq = seq1 + (size_t)b*NH*NPTS + n;
  float x[64];
  #pragma unroll
  for (int c = 0; c < 64; ++c) x[c] = sq[(size_t)c*NPTS];

  // phase 1: fc + bn1 + relu (o split across waves; exact chain per o)
  for (int oo = 0; oo < 16; ++oo) {
    const int o = w*16 + oo;
    float acc = 0.f;
    const float* ar = Wfc + o*64;
    #pragma unroll
    for (int c = 0; c < 64; c += 4) {
      float4 a4 = *(const float4*)(ar + c);
      acc = fmaf(a4.x, x[c],   acc);
      acc = fmaf(a4.y, x[c+1], acc);
      acc = fmaf(a4.z, x[c+2], acc);
      acc = fmaf(a4.w, x[c+3], acc);
    }
    float s1 = b1g[o] / sqrtf(b1v[o] + EPSV);
    float y  = (acc + bfc[o] - b1m[o]) * s1 + b1b[o];
    ptL[l*65 + o] = fmaxf(y, 0.f);
  }
  __syncthreads();
  float pt[64];
  #pragma unroll
  for (int c = 0; c < 64; ++c) pt[c] = ptL[l*65 + c];
  if (w == 0) {
    float s2 = 0.f;
    #pragma unroll
    for (int c = 0; c < 64; ++c) s2 = fmaf(pt[c], pt[c], s2);
    x2[(size_t)b*NPTS + n] = s2;
  }
  const size_t base = ((size_t)b*NPTS + n0)*NH;
  // coalesced flush of pts + ptsT (wave-split ranges)
  for (int t = w*16; t < w*16 + 16; ++t) pts[base + t*64 + l] = ptL[t*65 + l];
  for (int c = w*16; c < w*16 + 16; ++c)
    ptsT[((size_t)b*NH + c)*NPTS + n] = ptL[l*65 + c];
  __syncthreads();

  // phase 2a: G1 = pts . Wec[:, :64]^T (exact chain per o)
  for (int oo = 0; oo < 16; ++oo) {
    const int o = w*16 + oo;
    const float* w1 = Wec + o*128;
    float a1 = 0.f;
    #pragma unroll
    for (int c = 0; c < 64; c += 4) {
      float4 u = *(const float4*)(w1 + c);
      a1 = fmaf(u.x, pt[c],   a1); a1 = fmaf(u.y, pt[c+1], a1);
      a1 = fmaf(u.z, pt[c+2], a1); a1 = fmaf(u.w, pt[c+3], a1);
    }
    ptL[l*65 + o] = a1;
  }
  __syncthreads();
  for (int t = w*16; t < w*16 + 16; ++t) G1[base + t*64 + l] = ptL[t*65 + l];
  __syncthreads();

  // phase 2b: G2 = pts . Wec[:, 64:]^T (exact chain per o)
  for (int oo = 0; oo < 16; ++oo) {
    const int o = w*16 + oo;
    const float* w2 = Wec + o*128 + 64;
    float a2 = 0.f;
    #pragma unroll
    for (int c = 0; c < 64; c += 4) {
      float4 v = *(const float4*)(w2 + c);
      a2 = fmaf(v.x, pt[c],   a2); a2 = fmaf(v.y, pt[c+1], a2);
      a2 = fmaf(v.z, pt[c+2], a2); a2 = fmaf(v.w, pt[c+3], a2);
    }
    ptL[l*65 + o] = a2;
  }
  __syncthreads();
  for (int t = w*16; t < w*16 + 16; ++t) G2[base + t*64 + l] = ptL[t*65 + l];
}

// K2: lane-owns-row kNN. Block = 4 waves x 4 rows = 16 rows, all 2048 cols.
// __launch_bounds__(256, 1): this kernel NEEDS ~230 live VGPRs (128 acc +
// 32 prefetch staging + transients). R6 showed the backend's default
// occupancy heuristic allocates only 144 and spills ~23 MB/dispatch to
// scratch (VALUBusy 18%). waves-per-eu=1 unlocks the full 512-reg budget.
__global__ __launch_bounds__(256, 1) void k_knn(const float* __restrict__ pts,
                                                const float* __restrict__ ptsT,
                                                const float* __restrict__ x2,
                                                int* __restrict__ nidx) {
  const int lin = blockIdx.x;
  const int b  = ((lin & 7) << 1) | ((lin >> 3) & 1);  // XCD-local batches
  const int rg = lin >> 4;                              // 0..127
  const int tid = threadIdx.x, w = tid >> 6, l = tid & 63;
  const int r0 = rg*16 + w*4;

  __shared__ float colB[2][4*NPTS];   // 2 x 32 KB

  const float* Tb = ptsT + (size_t)b*NH*NPTS;
  const float* prow = pts + ((size_t)b*NPTS + r0)*NH;

  float a0[32], a1[32], a2[32], a3[32];
  #pragma unroll
  for (int j = 0; j < 32; ++j) { a0[j]=0.f; a1[j]=0.f; a2[j]=0.f; a3[j]=0.f; }

  { // prologue: stage chunk 0
    float4 st[8];
    #pragma unroll
    for (int s = 0; s < 8; ++s) st[s] = *(const float4*)(Tb + s*1024 + tid*4);
    #pragma unroll
    for (int s = 0; s < 8; ++s) *(float4*)(&colB[0][s*1024 + tid*4]) = st[s];
  }
  __syncthreads();

  #pragma unroll 1
  for (int t = 0; t < 16; ++t) {
    float4 nx[8];
    if (t < 15) { // issue next chunk's loads early (hide under FMA)
      const float* src = Tb + (size_t)(t+1)*8192;
      #pragma unroll
      for (int s = 0; s < 8; ++s) nx[s] = *(const float4*)(src + s*1024 + tid*4);
    }
    float4 rv0 = *(const float4*)(prow + 0*NH + t*4);
    float4 rv1 = *(const float4*)(prow + 1*NH + t*4);
    float4 rv2 = *(const float4*)(prow + 2*NH + t*4);
    float4 rv3 = *(const float4*)(prow + 3*NH + t*4);
    const float* cb = &colB[t & 1][0];
    #pragma unroll
    for (int k = 0; k < 4; ++k) {
      float4 f[8];
      #pragma unroll
      for (int jj = 0; jj < 8; ++jj)
        f[jj] = *(const float4*)(cb + k*NPTS + jj*256 + l*4);
      const float r0k = (k==0)?rv0.x:(k==1)?rv0.y:(k==2)?rv0.z:rv0.w;
      const float r1k = (k==0)?rv1.x:(k==1)?rv1.y:(k==2)?rv1.z:rv1.w;
      const float r2k = (k==0)?rv2.x:(k==1)?rv2.y:(k==2)?rv2.z:rv2.w;
      const float r3k = (k==0)?rv3.x:(k==1)?rv3.y:(k==2)?rv3.z:rv3.w;
      #pragma unroll
      for (int jj = 0; jj < 8; ++jj) {
        a0[jj*4+0] = fmaf(r0k, f[jj].x, a0[jj*4+0]);
        a0[jj*4+1] = fmaf(r0k, f[jj].y, a0[jj*4+1]);
        a0[jj*4+2] = fmaf(r0k, f[jj].z, a0[jj*4+2]);
        a0[jj*4+3] = fmaf(r0k, f[jj].w, a0[jj*4+3]);
        a1[jj*4+0] = fmaf(r1k, f[jj].x, a1[jj*4+0]);
        a1[jj*4+1] = fmaf(r1k, f[jj].y, a1[jj*4+1]);
        a1[jj*4+2] = fmaf(r1k, f[jj].z, a1[jj*4+2]);
        a1[jj*4+3] = fmaf(r1k, f[jj].w, a1[jj*4+3]);
        a2[jj*4+0] = fmaf(r2k, f[jj].x, a2[jj*4+0]);
        a2[jj*4+1] = fmaf(r2k, f[jj].y, a2[jj*4+1]);
        a2[jj*4+2] = fmaf(r2k, f[jj].z, a2[jj*4+2]);
        a2[jj*4+3] = fmaf(r2k, f[jj].w, a2[jj*4+3]);
        a3[jj*4+0] = fmaf(r3k, f[jj].x, a3[jj*4+0]);
        a3[jj*4+1] = fmaf(r3k, f[jj].y, a3[jj*4+1]);
        a3[jj*4+2] = fmaf(r3k, f[jj].z, a3[jj*4+2]);
        a3[jj*4+3] = fmaf(r3k, f[jj].w, a3[jj*4+3]);
      }
    }
    if (t < 15) { // write staged regs to the other buffer
      #pragma unroll
      for (int s = 0; s < 8; ++s)
        *(float4*)(&colB[(t+1)&1][s*1024 + tid*4]) = nx[s];
    }
    __syncthreads();
  }

  // selection: key = 2*dot - x2[col] (row term rank-invariant; same as R4)
  float x2v[32];
  #pragma unroll
  for (int jj = 0; jj < 8; ++jj)
    *(float4*)(&x2v[jj*4]) = *(const float4*)(x2 + (size_t)b*NPTS + jj*256 + l*4);

  #pragma unroll 1
  for (int r = 0; r < 4; ++r) {
    float tmp[32];
    #pragma unroll
    for (int j = 0; j < 32; ++j)
      tmp[j] = (r == 0) ? a0[j] : (r == 1) ? a1[j] : (r == 2) ? a2[j] : a3[j];

    // per-lane sorted-4 build; stream (j asc) is col-asc so strict '>'
    // preserves the idx-asc tie-break; (bv,bi) = best element ever discarded
    float L0v=NINF,L1v=NINF,L2v=NINF,L3v=NINF;
    int   L0i=0x7fffffff,L1i=0x7fffffff,L2i=0x7fffffff,L3i=0x7fffffff;
    float bv = NINF; int bi = 0x7fffffff;
    #pragma unroll
    for (int j = 0; j < 32; ++j) {
      float cv = fmaf(2.0f, tmp[j], -x2v[j]);
      int   ci = ((j >> 2) << 8) + (j & 3) + (l << 2);
      { bool c = cv > L0v; float nv=c?cv:L0v; int ni=c?ci:L0i; float ov=L0v; int oi=L0i; cv=c?ov:cv; ci=c?oi:ci; L0v=nv; L0i=ni; }
      { bool c = cv > L1v; float nv=c?cv:L1v; int ni=c?ci:L1i; float ov=L1v; int oi=L1i; cv=c?ov:cv; ci=c?oi:ci; L1v=nv; L1i=ni; }
      { bool c = cv > L2v; float nv=c?cv:L2v; int ni=c?ci:L2i; float ov=L2v; int oi=L2i; cv=c?ov:cv; ci=c?oi:ci; L2v=nv; L2i=ni; }
      { bool c = cv > L3v; float nv=c?cv:L3v; int ni=c?ci:L3i; float ov=L3v; int oi=L3i; cv=c?ov:cv; ci=c?oi:ci; L3v=nv; L3i=ni; }
      bool bb = better(cv, ci, bv, bi);
      bv = bb ? cv : bv; bi = bb ? ci : bi;
    }

    // 20x wave-argmax extraction
    float h0=L0v,h1=L1v,h2=L2v,h3=L3v;
    int   e0=L0i,e1=L1i,e2=L2i,e3=L3i;
    int myNb = 0;
    float lastv = NINF; int lasti = 0x7fffffff;
    #pragma unroll 1
    for (int t20 = 0; t20 < NEIGHS; ++t20) {
      float gv = h0; int gi = e0;
      #pragma unroll
      for (int m = 32; m >= 1; m >>= 1) {
        float ov = __shfl_xor(gv, m, 64);
        int   oi = __shfl_xor(gi, m, 64);
        bool bt = better(ov, oi, gv, gi);
        gv = bt ? ov : gv; gi = bt ? oi : gi;
      }
      bool win = (h0 == gv) && (e0 == gi);
      h0 = win ? h1 : h0; e0 = win ? e1 : e0;
      h1 = win ? h2 : h1; e1 = win ? e2 : e1;
      h2 = win ? h3 : h2; e2 = win ? e3 : e2;
      h3 = win ? NINF : h3; e3 = win ? 0x7fffffff : e3;
      if (l == t20) myNb = gi;
      lastv = gv; lasti = gi;
    }
    // airtight check: if any lane's best-discarded beats the 20th pick,
    // re-extract this row exactly from the full streams (rare)
    bool flag = better(bv, bi, lastv, lasti);
    if (__any((int)flag)) {
      unsigned taken = 0u;
      #pragma unroll 1
      for (int t20 = 0; t20 < NEIGHS; ++t20) {
        float pv = NINF; int pi = 0x7fffffff; int pj = 0;
        #pragma unroll
        for (int j = 0; j < 32; ++j) {
          float kv = fmaf(2.0f, tmp[j], -x2v[j]);
          int   ci = ((j >> 2) << 8) + (j & 3) + (l << 2);
          bool av2 = ((taken >> j) & 1u) == 0u;
          bool bt = av2 && better(kv, ci, pv, pi);
          pv = bt ? kv : pv; pi = bt ? ci : pi; pj = bt ? j : pj;
        }
        float gv = pv; int gi = pi;
        #pragma unroll
        for (int m = 32; m >= 1; m >>= 1) {
          float ov = __shfl_xor(gv, m, 64);
          int   oi = __shfl_xor(gi, m, 64);
          bool bt = better(ov, oi, gv, gi);
          gv = bt ? ov : gv; gi = bt ? oi : gi;
        }
        if ((pv == gv) && (pi == gi)) taken |= (1u << pj);
        if (l == t20) myNb = gi;
      }
    }
    if (l < NEIGHS) nidx[((size_t)b*NPTS + r0 + r)*NEIGHS + l] = myNb;
  }
}

// K3: per-point neighbor max -> X -> v = Wb@X -> sc1/sc2/ret. One wave per point.
__global__ __launch_bounds__(256) void k_score(const float* __restrict__ pts,
    const float* __restrict__ G1, const float* __restrict__ G2,
    const int* __restrict__ nidx, const int* __restrict__ perm,
    const float* __restrict__ Wb,
    const float* __restrict__ b2g, const float* __restrict__ b2b,
    const float* __restrict__ b2m, const float* __restrict__ b2v,
    const float* __restrict__ bb,
    float* __restrict__ sc1w, float* __restrict__ out) {
  const int b = blockIdx.y;
  const int n0 = blockIdx.x * 16;
  const int tid = threadIdx.x, l = tid & 63, w = tid >> 6;
  __shared__ float WbS[64*65];
  for (int i = tid; i < 64*64; i += 256) WbS[(i >> 6)*65 + (i & 63)] = Wb[i];
  __syncthreads();
  const float sc2v = b2g[l] / sqrtf(b2v[l] + EPSV);
  const float mean2 = b2m[l], beta2 = b2b[l];
  const float bbv = bb[0];
  const float* G1b = G1 + (size_t)b*NPTS*NH;
  for (int it = 0; it < 4; ++it) {
    const int n = n0 + it*4 + w;
    const size_t ro = (size_t)b*NPTS*NH + (size_t)n*NH;
    const float base = G2[ro + l] - G1[ro + l];
    const int* nb = nidx + ((size_t)b*NPTS + n)*NEIGHS;
    float mx = NINF;
    #pragma unroll
    for (int k = 0; k < NEIGHS; ++k) {
      int m = nb[k];
      float val = G1b[(size_t)m*NH + l] + base;
      float y = (val - mean2) * sc2v + beta2;
      y = (y >= 0.f) ? y : 0.2f*y;
      mx = fmaxf(mx, y);
    }
    float X = 1.f / (1.f + expf(-mx));
    double v = 0.0;
    #pragma unroll
    for (int d = 0; d < 64; ++d) {
      float xd = __shfl(X, d, 64);
      v += (double)WbS[l*65 + d] * (double)xd;
    }
    float p1 = pts[ro + l];
    int pn = perm[n];
    float p2 = pts[(size_t)b*NPTS*NH + (size_t)pn*NH + l];
    double s1 = (double)p1 * v;
    double s2 = (double)p2 * v;
    #pragma unroll
    for (int off = 32; off > 0; off >>= 1) {
      s1 += __shfl_xor(s1, off, 64);
      s2 += __shfl_xor(s2, off, 64);
    }
    if (l == 0) {
      float r1 = (float)(s1 + (double)bbv);
      float r2 = (float)(s2 + (double)bbv);
      sc1w[(size_t)b*NPTS + n] = r1;
      out[OFF_RET + (size_t)b*2*NPTS + n] = r1;
      out[OFF_RET + (size_t)b*2*NPTS + NPTS + n] = r2;
    }
  }
}

// K4: per-batch exact top-512 (value desc, idx asc) via u64 bitonic sort + gathers
__global__ __launch_bounds__(256) void k_select(const float* __restrict__ sc1w,
    const float* __restrict__ seq1, const float* __restrict__ xyz,
    float* __restrict__ out) {
  const int b = blockIdx.x, tid = threadIdx.x;
  __shared__ unsigned long long keys[NPTS];
  __shared__ float valS[KSEL];
  __shared__ int idxS[KSEL];
  for (int i = tid; i < NPTS; i += 256) {
    float f = sc1w[(size_t)b*NPTS + i];
    unsigned u = __float_as_uint(f);
    u = (u & 0x80000000u) ? ~u : (u | 0x80000000u);
    keys[i] = ((unsigned long long)(~u) << 32) | (unsigned)i;
  }
  __syncthreads();
  for (int k = 2; k <= NPTS; k <<= 1) {
    for (int j = k >> 1; j > 0; j >>= 1) {
      for (int i = tid; i < NPTS; i += 256) {
        int l2 = i ^ j;
        if (l2 > i) {
          unsigned long long a = keys[i], c = keys[l2];
          bool up = ((i & k) == 0);
          if ((a > c) == up) { keys[i] = c; keys[l2] = a; }
        }
      }
      __syncthreads();
    }
  }
  for (int i = tid; i < KSEL; i += 256) {
    unsigned long long key = keys[i];
    int sidx = (int)(key & 0xffffffffULL);
    unsigned u = ~(unsigned)(key >> 32);
    unsigned fb = (u & 0x80000000u) ? (u & 0x7fffffffu) : ~u;
    float f = __uint_as_float(fb);
    float val = 1.f / (1.f + expf(-f));
    valS[i] = val; idxS[i] = sidx;
    out[OFF_VAL + (size_t)b*KSEL + i] = val;
    out[OFF_IDX + (size_t)b*KSEL + i] = (float)sidx;
  }
  __syncthreads();
  for (int t = tid; t < NH*KSEL; t += 256) {
    int c = t >> 9, i = t & (KSEL-1);
    float sv = seq1[((size_t)b*NH + c)*NPTS + idxS[i]];
    out[OFF_SEQ + (((size_t)b*NH + c) << 9) + i] = sv * valS[i];
  }
  for (int t = tid; t < 3*KSEL; t += 256) {
    int c = t >> 9, i = t & (KSEL-1);
    float xv = xyz[((size_t)b*3 + c)*NPTS + idxS[i]];
    out[OFF_XST + (((size_t)b*3 + c) << 9) + i] = xv;
    out[OFF_XO  + (((size_t)b*3 + c) << 9) + i] = xv * valS[i];
  }
}

extern "C" void kernel_launch(void* const* d_in, const int* in_sizes, int n_in,
                              void* d_out, int out_size, void* d_ws, size_t ws_size,
                              hipStream_t stream) {
  const float* xyz  = (const float*)d_in[0];
  const float* seq1 = (const float*)d_in[1];
  const int*   perm = (const int*)d_in[2];
  const float* Wfc  = (const float*)d_in[3];
  const float* bfc  = (const float*)d_in[4];
  const float* b1g  = (const float*)d_in[5];
  const float* b1b  = (const float*)d_in[6];
  const float* b1m  = (const float*)d_in[7];
  const float* b1v  = (const float*)d_in[8];
  const float* Wec  = (const float*)d_in[9];
  const float* b2g  = (const float*)d_in[10];
  const float* b2b  = (const float*)d_in[11];
  const float* b2m  = (const float*)d_in[12];
  const float* b2v  = (const float*)d_in[13];
  const float* Wb   = (const float*)d_in[14];
  const float* bb   = (const float*)d_in[15];
  float* out = (float*)d_out;

  float* ws   = (float*)d_ws;
  float* pts  = ws;
  float* ptsT = pts + (size_t)NB*NPTS*NH;
  float* G1   = ptsT + (size_t)NB*NPTS*NH;
  float* G2   = G1  + (size_t)NB*NPTS*NH;
  float* x2   = G2  + (size_t)NB*NPTS*NH;
  float* sc1w = x2  + (size_t)NB*NPTS;
  int*   nidx = (int*)(sc1w + (size_t)NB*NPTS);

  hipLaunchKernelGGL(k_fc, dim3(NPTS/64, NB), dim3(256), 0, stream,
                     seq1, Wfc, bfc, b1g, b1b, b1m, b1v, Wec, pts, ptsT, G1, G2, x2);
  hipLaunchKernelGGL(k_knn, dim3(NB*NPTS/16), dim3(256), 0, stream,
                     pts, ptsT, x2, nidx);
  hipLaunchKernelGGL(k_score, dim3(NPTS/16, NB), dim3(256), 0, stream,
                     pts, G1, G2, nidx, perm, Wb, b2g, b2b, b2m, b2v, bb, sc1w, out);
  hipLaunchKernelGGL(k_select, dim3(NB), dim3(256), 0, stream,
                     sc1w, seq1, xyz, out);
}

// Round 8
// 783.658 us; speedup vs baseline: 1.4326x; 1.4295x over previous
//
#include <hip/hip_runtime.h>
#include <math.h>

#define NB 16
#define NH 64
#define NPTS 2048
#define NEIGHS 20
#define KSEL 512
#define EPSV 1e-5f
#define NINF -3.0e38f

// output layout (floats), reference return order
#define OFF_SEQ 0
#define OFF_VAL (NB*NH*KSEL)            // 524288
#define OFF_IDX (OFF_VAL + NB*KSEL)     // 532480
#define OFF_RET (OFF_IDX + NB*KSEL)     // 540672
#define OFF_XST (OFF_RET + NB*2*NPTS)   // 606208
#define OFF_XO  (OFF_XST + NB*3*KSEL)   // 630784

__device__ __forceinline__ bool better(float av, int ai, float bv, int bi) {
  return (av > bv) || (av == bv && ai < bi);
}

// K1: pts = relu(bn1(Wfc@seq1 + bfc)), plus x2, G1, G2, and ptsT [b][c][n].
// (unchanged from the passing R7 kernel)
__global__ __launch_bounds__(256) void k_fc(const float* __restrict__ seq1,
                                            const float* __restrict__ Wfc,
                                            const float* __restrict__ bfc,
                                            const float* __restrict__ b1g,
                                            const float* __restrict__ b1b,
                                            const float* __restrict__ b1m,
                                            const float* __restrict__ b1v,
                                            const float* __restrict__ Wec,
                                            float* __restrict__ pts,
                                            float* __restrict__ ptsT,
                                            float* __restrict__ G1,
                                            float* __restrict__ G2,
                                            float* __restrict__ x2) {
  const int b = blockIdx.y, n0 = blockIdx.x * 64;
  const int tid = threadIdx.x, l = tid & 63, w = tid >> 6;
  const int n = n0 + l;
  __shared__ float ptL[64*65];
  const float* sq = seq1 + (size_t)b*NH*NPTS + n;
  float x[64];
  #pragma unroll
  for (int c = 0; c < 64; ++c) x[c] = sq[(size_t)c*NPTS];

  for (int oo = 0; oo < 16; ++oo) {
    const int o = w*16 + oo;
    float acc = 0.f;
    const float* ar = Wfc + o*64;
    #pragma unroll
    for (int c = 0; c < 64; c += 4) {
      float4 a4 = *(const float4*)(ar + c);
      acc = fmaf(a4.x, x[c],   acc);
      acc = fmaf(a4.y, x[c+1], acc);
      acc = fmaf(a4.z, x[c+2], acc);
      acc = fmaf(a4.w, x[c+3], acc);
    }
    float s1 = b1g[o] / sqrtf(b1v[o] + EPSV);
    float y  = (acc + bfc[o] - b1m[o]) * s1 + b1b[o];
    ptL[l*65 + o] = fmaxf(y, 0.f);
  }
  __syncthreads();
  float pt[64];
  #pragma unroll
  for (int c = 0; c < 64; ++c) pt[c] = ptL[l*65 + c];
  if (w == 0) {
    float s2 = 0.f;
    #pragma unroll
    for (int c = 0; c < 64; ++c) s2 = fmaf(pt[c], pt[c], s2);
    x2[(size_t)b*NPTS + n] = s2;
  }
  const size_t base = ((size_t)b*NPTS + n0)*NH;
  for (int t = w*16; t < w*16 + 16; ++t) pts[base + t*64 + l] = ptL[t*65 + l];
  for (int c = w*16; c < w*16 + 16; ++c)
    ptsT[((size_t)b*NH + c)*NPTS + n] = ptL[l*65 + c];
  __syncthreads();

  for (int oo = 0; oo < 16; ++oo) {
    const int o = w*16 + oo;
    const float* w1 = Wec + o*128;
    float a1 = 0.f;
    #pragma unroll
    for (int c = 0; c < 64; c += 4) {
      float4 u = *(const float4*)(w1 + c);
      a1 = fmaf(u.x, pt[c],   a1); a1 = fmaf(u.y, pt[c+1], a1);
      a1 = fmaf(u.z, pt[c+2], a1); a1 = fmaf(u.w, pt[c+3], a1);
    }
    ptL[l*65 + o] = a1;
  }
  __syncthreads();
  for (int t = w*16; t < w*16 + 16; ++t) G1[base + t*64 + l] = ptL[t*65 + l];
  __syncthreads();

  for (int oo = 0; oo < 16; ++oo) {
    const int o = w*16 + oo;
    const float* w2 = Wec + o*128 + 64;
    float a2 = 0.f;
    #pragma unroll
    for (int c = 0; c < 64; c += 4) {
      float4 v = *(const float4*)(w2 + c);
      a2 = fmaf(v.x, pt[c],   a2); a2 = fmaf(v.y, pt[c+1], a2);
      a2 = fmaf(v.z, pt[c+2], a2); a2 = fmaf(v.w, pt[c+3], a2);
    }
    ptL[l*65 + o] = a2;
  }
  __syncthreads();
  for (int t = w*16; t < w*16 + 16; ++t) G2[base + t*64 + l] = ptL[t*65 + l];
}

// ---- K2 helper macros (all values in NAMED registers; zero arrays) ----
#define FMA4(A, s, F) { (A).x = fmaf((s),(F).x,(A).x); (A).y = fmaf((s),(F).y,(A).y); \
                        (A).z = fmaf((s),(F).z,(A).z); (A).w = fmaf((s),(F).w,(A).w); }

#define CAND(KV, CI) { float cv_=(KV); int ci_=(CI); \
  { bool c_=cv_>L0v; float nv_=c_?cv_:L0v; int ni_=c_?ci_:L0i; float ov_=L0v; int oi_=L0i; cv_=c_?ov_:cv_; ci_=c_?oi_:ci_; L0v=nv_; L0i=ni_; } \
  { bool c_=cv_>L1v; float nv_=c_?cv_:L1v; int ni_=c_?ci_:L1i; float ov_=L1v; int oi_=L1i; cv_=c_?ov_:cv_; ci_=c_?oi_:ci_; L1v=nv_; L1i=ni_; } \
  { bool c_=cv_>L2v; float nv_=c_?cv_:L2v; int ni_=c_?ci_:L2i; float ov_=L2v; int oi_=L2i; cv_=c_?ov_:cv_; ci_=c_?oi_:ci_; L2v=nv_; L2i=ni_; } \
  { bool c_=cv_>L3v; float nv_=c_?cv_:L3v; int ni_=c_?ci_:L3i; float ov_=L3v; int oi_=L3i; cv_=c_?ov_:cv_; ci_=c_?oi_:ci_; L3v=nv_; L3i=ni_; } \
  bool bb_=better(cv_,ci_,bv,bi); bv=bb_?cv_:bv; bi=bb_?ci_:bi; }

#define FCAND(JB, AV, XV) { bool av_=((taken_>>(JB))&1u)==0u; float kv_=fmaf(2.f,(AV),-(XV)); \
  int ci_=cbase+((JB)>>2)*256+((JB)&3); bool bt_=av_&&better(kv_,ci_,pv,pi); \
  pv=bt_?kv_:pv; pi=bt_?ci_:pi; pj=bt_?(JB):pj; }

// Exact top-20 of this wave's 1024-col half for one row, then store sorted
// list to LDS. Build: per-lane sorted-4 (+best-discarded); extract: 20x
// wave-argmax; airtight fallback re-extracts if any discard could matter.
#define SELROW(T0,T1,T2,T3,RI) { \
  float L0v=NINF,L1v=NINF,L2v=NINF,L3v=NINF; \
  int   L0i=0x7fffffff,L1i=0x7fffffff,L2i=0x7fffffff,L3i=0x7fffffff; \
  float bv=NINF; int bi=0x7fffffff; \
  CAND(fmaf(2.f,(T0).x,-x0.x), cbase+0)   CAND(fmaf(2.f,(T0).y,-x0.y), cbase+1) \
  CAND(fmaf(2.f,(T0).z,-x0.z), cbase+2)   CAND(fmaf(2.f,(T0).w,-x0.w), cbase+3) \
  CAND(fmaf(2.f,(T1).x,-x1.x), cbase+256) CAND(fmaf(2.f,(T1).y,-x1.y), cbase+257) \
  CAND(fmaf(2.f,(T1).z,-x1.z), cbase+258) CAND(fmaf(2.f,(T1).w,-x1.w), cbase+259) \
  CAND(fmaf(2.f,(T2).x,-x2q.x), cbase+512) CAND(fmaf(2.f,(T2).y,-x2q.y), cbase+513) \
  CAND(fmaf(2.f,(T2).z,-x2q.z), cbase+514) CAND(fmaf(2.f,(T2).w,-x2q.w), cbase+515) \
  CAND(fmaf(2.f,(T3).x,-x3.x), cbase+768) CAND(fmaf(2.f,(T3).y,-x3.y), cbase+769) \
  CAND(fmaf(2.f,(T3).z,-x3.z), cbase+770) CAND(fmaf(2.f,(T3).w,-x3.w), cbase+771) \
  float h0v=L0v,h1v=L1v,h2v=L2v,h3v=L3v; \
  int   e0_=L0i,e1_=L1i,e2_=L2i,e3_=L3i; \
  float myV_=0.f; int myNb_=0; float lastv_=NINF; int lasti_=0x7fffffff; \
  for (int t20_=0; t20_<NEIGHS; ++t20_) { \
    float gv=h0v; int gi=e0_; \
    for (int m_=32; m_>=1; m_>>=1) { \
      float ov=__shfl_xor(gv,m_,64); int oi=__shfl_xor(gi,m_,64); \
      bool bt=better(ov,oi,gv,gi); gv=bt?ov:gv; gi=bt?oi:gi; } \
    bool win=(h0v==gv)&&(e0_==gi); \
    h0v=win?h1v:h0v; e0_=win?e1_:e0_; h1v=win?h2v:h1v; e1_=win?e2_:e1_; \
    h2v=win?h3v:h2v; e2_=win?e3_:e2_; h3v=win?NINF:h3v; e3_=win?0x7fffffff:e3_; \
    if (l==t20_){myV_=gv;myNb_=gi;} lastv_=gv; lasti_=gi; \
  } \
  bool flag_ = better(bv, bi, lastv_, lasti_); \
  if (__any((int)flag_)) { \
    unsigned taken_ = 0u; \
    for (int t20_=0; t20_<NEIGHS; ++t20_) { \
      float pv=NINF; int pi=0x7fffffff; int pj=0; \
      FCAND(0,(T0).x,x0.x)  FCAND(1,(T0).y,x0.y)  FCAND(2,(T0).z,x0.z)  FCAND(3,(T0).w,x0.w) \
      FCAND(4,(T1).x,x1.x)  FCAND(5,(T1).y,x1.y)  FCAND(6,(T1).z,x1.z)  FCAND(7,(T1).w,x1.w) \
      FCAND(8,(T2).x,x2q.x) FCAND(9,(T2).y,x2q.y) FCAND(10,(T2).z,x2q.z) FCAND(11,(T2).w,x2q.w) \
      FCAND(12,(T3).x,x3.x) FCAND(13,(T3).y,x3.y) FCAND(14,(T3).z,x3.z) FCAND(15,(T3).w,x3.w) \
      float gv=pv; int gi=pi; \
      for (int m_=32; m_>=1; m_>>=1) { \
        float ov=__shfl_xor(gv,m_,64); int oi=__shfl_xor(gi,m_,64); \
        bool bt=better(ov,oi,gv,gi); gv=bt?ov:gv; gi=bt?oi:gi; } \
      if ((pv==gv)&&(pi==gi)) taken_ |= (1u<<pj); \
      if (l==t20_){myV_=gv;myNb_=gi;} \
    } \
  } \
  if (l < NEIGHS) { \
    mrgV[((g*4+(RI))*2+h)*20 + l] = myV_; \
    mrgI[((g*4+(RI))*2+h)*20 + l] = myNb_; \
  } }

// K2: 8 waves x (4 rows, 16 cols/lane). 64 named float4-component
// accumulators (zero arrays -> zero scratch). Rows in LDS (lgkm-only
// reads). Cols double-buffered with T14 issue-early/write-late staging.
// Two waves cover each row (col halves); exact 2-pointer merge of the
// two sorted-20 lists at the end.
__global__ __launch_bounds__(512, 2) void k_knn(const float* __restrict__ pts,
                                                const float* __restrict__ ptsT,
                                                const float* __restrict__ x2,
                                                int* __restrict__ nidx) {
  const int lin = blockIdx.x;
  const int b  = ((lin & 7) << 1) | ((lin >> 3) & 1);  // XCD-local batches
  const int rg = lin >> 4;                              // 0..127
  const int tid = threadIdx.x, w = tid >> 6, l = tid & 63;
  const int g = w >> 1, h = w & 1;     // row group 0..3, col half 0..1
  const int r0 = rg*16;

  __shared__ float colB[2][8192];      // 64 KB: [buf][k(4)][col(2048)]
  __shared__ float rowS[16*64];        // 4 KB
  __shared__ float mrgV[16*2*20];      // 2.5 KB
  __shared__ int   mrgI[16*2*20];      // 2.5 KB

  const float* Tb = ptsT + (size_t)b*NH*NPTS;

  // stage 16 row vectors (1024 floats)
  if (tid < 256) {
    int rr = tid >> 4, c4 = (tid & 15) * 4;
    *(float4*)&rowS[rr*64 + c4] =
        *(const float4*)(pts + ((size_t)b*NPTS + r0 + rr)*NH + c4);
  }
  // stage chunk 0
  #pragma unroll
  for (int s = 0; s < 4; ++s) {
    float4 v = *(const float4*)(Tb + (w*4+s)*256 + l*4);
    *(float4*)&colB[0][(w*4+s)*256 + l*4] = v;
  }
  __syncthreads();

  float4 A00={0,0,0,0},A01={0,0,0,0},A02={0,0,0,0},A03={0,0,0,0};
  float4 A10={0,0,0,0},A11={0,0,0,0},A12={0,0,0,0},A13={0,0,0,0};
  float4 A20={0,0,0,0},A21={0,0,0,0},A22={0,0,0,0},A23={0,0,0,0};
  float4 A30={0,0,0,0},A31={0,0,0,0},A32={0,0,0,0},A33={0,0,0,0};

  #pragma unroll 1
  for (int t = 0; t < 16; ++t) {
    // T14 issue-early: next chunk's global loads (hidden under FMA)
    float4 st0, st1, st2, st3;
    if (t < 15) {
      const float* src = Tb + (size_t)(t+1)*8192 + w*1024 + l*4;
      st0 = *(const float4*)(src);
      st1 = *(const float4*)(src + 256);
      st2 = *(const float4*)(src + 512);
      st3 = *(const float4*)(src + 768);
    }
    const float* cb = &colB[t & 1][h*1024 + l*4];
    const float* rs = &rowS[(g*4)*64 + t*4];   // wave-uniform (lgkm only)
    #pragma unroll
    for (int k = 0; k < 4; ++k) {
      float4 f0 = *(const float4*)(cb + k*2048);
      float4 f1 = *(const float4*)(cb + k*2048 + 256);
      float4 f2 = *(const float4*)(cb + k*2048 + 512);
      float4 f3 = *(const float4*)(cb + k*2048 + 768);
      float r0k = rs[k], r1k = rs[64 + k], r2k = rs[128 + k], r3k = rs[192 + k];
      FMA4(A00,r0k,f0) FMA4(A01,r0k,f1) FMA4(A02,r0k,f2) FMA4(A03,r0k,f3)
      FMA4(A10,r1k,f0) FMA4(A11,r1k,f1) FMA4(A12,r1k,f2) FMA4(A13,r1k,f3)
      FMA4(A20,r2k,f0) FMA4(A21,r2k,f1) FMA4(A22,r2k,f2) FMA4(A23,r2k,f3)
      FMA4(A30,r3k,f0) FMA4(A31,r3k,f1) FMA4(A32,r3k,f2) FMA4(A33,r3k,f3)
    }
    // write-late: land staged regs into the other buffer
    if (t < 15) {
      float* d = &colB[(t+1)&1][w*1024 + l*4];
      *(float4*)(d)       = st0;
      *(float4*)(d + 256) = st1;
      *(float4*)(d + 512) = st2;
      *(float4*)(d + 768) = st3;
    }
    __syncthreads();
  }

  // selection keys: 2*dot - x2[col] (row term rank-invariant)
  const int cbase = h*1024 + l*4;
  const float* x2b = x2 + (size_t)b*NPTS + cbase;
  float4 x0  = *(const float4*)(x2b);
  float4 x1  = *(const float4*)(x2b + 256);
  float4 x2q = *(const float4*)(x2b + 512);
  float4 x3  = *(const float4*)(x2b + 768);

  SELROW(A00,A01,A02,A03,0)
  SELROW(A10,A11,A12,A13,1)
  SELROW(A20,A21,A22,A23,2)
  SELROW(A30,A31,A32,A33,3)

  __syncthreads();
  // exact stable merge of the two sorted-20 half-lists per row
  if (w == 0 && l < 16) {
    const float* va = &mrgV[(l*2+0)*20]; const int* ja = &mrgI[(l*2+0)*20];
    const float* vb = &mrgV[(l*2+1)*20]; const int* jb = &mrgI[(l*2+1)*20];
    int* dst = nidx + ((size_t)b*NPTS + r0 + l)*NEIGHS;
    int ia = 0, ib = 0;
    #pragma unroll 1
    for (int k = 0; k < NEIGHS; ++k) {
      float av = va[ia]; int ai = ja[ia];
      float bv2 = vb[ib]; int bi2 = jb[ib];
      bool ta = better(av, ai, bv2, bi2);
      dst[k] = ta ? ai : bi2;
      ia += ta ? 1 : 0; ib += ta ? 0 : 1;
    }
  }
}

// K3: per-point neighbor max -> X -> v = Wb@X -> sc1/sc2/ret. (unchanged)
__global__ __launch_bounds__(256) void k_score(const float* __restrict__ pts,
    const float* __restrict__ G1, const float* __restrict__ G2,
    const int* __restrict__ nidx, const int* __restrict__ perm,
    const float* __restrict__ Wb,
    const float* __restrict__ b2g, const float* __restrict__ b2b,
    const float* __restrict__ b2m, const float* __restrict__ b2v,
    const float* __restrict__ bb,
    float* __restrict__ sc1w, float* __restrict__ out) {
  const int b = blockIdx.y;
  const int n0 = blockIdx.x * 16;
  const int tid = threadIdx.x, l = tid & 63, w = tid >> 6;
  __shared__ float WbS[64*65];
  for (int i = tid; i < 64*64; i += 256) WbS[(i >> 6)*65 + (i & 63)] = Wb[i];
  __syncthreads();
  const float sc2v = b2g[l] / sqrtf(b2v[l] + EPSV);
  const float mean2 = b2m[l], beta2 = b2b[l];
  const float bbv = bb[0];
  const float* G1b = G1 + (size_t)b*NPTS*NH;
  for (int it = 0; it < 4; ++it) {
    const int n = n0 + it*4 + w;
    const size_t ro = (size_t)b*NPTS*NH + (size_t)n*NH;
    const float base = G2[ro + l] - G1[ro + l];
    const int* nb = nidx + ((size_t)b*NPTS + n)*NEIGHS;
    float mx = NINF;
    #pragma unroll
    for (int k = 0; k < NEIGHS; ++k) {
      int m = nb[k];
      float val = G1b[(size_t)m*NH + l] + base;
      float y = (val - mean2) * sc2v + beta2;
      y = (y >= 0.f) ? y : 0.2f*y;
      mx = fmaxf(mx, y);
    }
    float X = 1.f / (1.f + expf(-mx));
    double v = 0.0;
    #pragma unroll
    for (int d = 0; d < 64; ++d) {
      float xd = __shfl(X, d, 64);
      v += (double)WbS[l*65 + d] * (double)xd;
    }
    float p1 = pts[ro + l];
    int pn = perm[n];
    float p2 = pts[(size_t)b*NPTS*NH + (size_t)pn*NH + l];
    double s1 = (double)p1 * v;
    double s2 = (double)p2 * v;
    #pragma unroll
    for (int off = 32; off > 0; off >>= 1) {
      s1 += __shfl_xor(s1, off, 64);
      s2 += __shfl_xor(s2, off, 64);
    }
    if (l == 0) {
      float r1 = (float)(s1 + (double)bbv);
      float r2 = (float)(s2 + (double)bbv);
      sc1w[(size_t)b*NPTS + n] = r1;
      out[OFF_RET + (size_t)b*2*NPTS + n] = r1;
      out[OFF_RET + (size_t)b*2*NPTS + NPTS + n] = r2;
    }
  }
}

// K4: per-batch exact top-512 via u64 bitonic sort + gathers. (unchanged)
__global__ __launch_bounds__(256) void k_select(const float* __restrict__ sc1w,
    const float* __restrict__ seq1, const float* __restrict__ xyz,
    float* __restrict__ out) {
  const int b = blockIdx.x, tid = threadIdx.x;
  __shared__ unsigned long long keys[NPTS];
  __shared__ float valS[KSEL];
  __shared__ int idxS[KSEL];
  for (int i = tid; i < NPTS; i += 256) {
    float f = sc1w[(size_t)b*NPTS + i];
    unsigned u = __float_as_uint(f);
    u = (u & 0x80000000u) ? ~u : (u | 0x80000000u);
    keys[i] = ((unsigned long long)(~u) << 32) | (unsigned)i;
  }
  __syncthreads();
  for (int k = 2; k <= NPTS; k <<= 1) {
    for (int j = k >> 1; j > 0; j >>= 1) {
      for (int i = tid; i < NPTS; i += 256) {
        int l2 = i ^ j;
        if (l2 > i) {
          unsigned long long a = keys[i], c = keys[l2];
          bool up = ((i & k) == 0);
          if ((a > c) == up) { keys[i] = c; keys[l2] = a; }
        }
      }
      __syncthreads();
    }
  }
  for (int i = tid; i < KSEL; i += 256) {
    unsigned long long key = keys[i];
    int sidx = (int)(key & 0xffffffffULL);
    unsigned u = ~(unsigned)(key >> 32);
    unsigned fb = (u & 0x80000000u) ? (u & 0x7fffffffu) : ~u;
    float f = __uint_as_float(fb);
    float val = 1.f / (1.f + expf(-f));
    valS[i] = val; idxS[i] = sidx;
    out[OFF_VAL + (size_t)b*KSEL + i] = val;
    out[OFF_IDX + (size_t)b*KSEL + i] = (float)sidx;
  }
  __syncthreads();
  for (int t = tid; t < NH*KSEL; t += 256) {
    int c = t >> 9, i = t & (KSEL-1);
    float sv = seq1[((size_t)b*NH + c)*NPTS + idxS[i]];
    out[OFF_SEQ + (((size_t)b*NH + c) << 9) + i] = sv * valS[i];
  }
  for (int t = tid; t < 3*KSEL; t += 256) {
    int c = t >> 9, i = t & (KSEL-1);
    float xv = xyz[((size_t)b*3 + c)*NPTS + idxS[i]];
    out[OFF_XST + (((size_t)b*3 + c) << 9) + i] = xv;
    out[OFF_XO  + (((size_t)b*3 + c) << 9) + i] = xv * valS[i];
  }
}

extern "C" void kernel_launch(void* const* d_in, const int* in_sizes, int n_in,
                              void* d_out, int out_size, void* d_ws, size_t ws_size,
                              hipStream_t stream) {
  const float* xyz  = (const float*)d_in[0];
  const float* seq1 = (const float*)d_in[1];
  const int*   perm = (const int*)d_in[2];
  const float* Wfc  = (const float*)d_in[3];
  const float* bfc  = (const float*)d_in[4];
  const float* b1g  = (const float*)d_in[5];
  const float* b1b  = (const float*)d_in[6];
  const float* b1m  = (const float*)d_in[7];
  const float* b1v  = (const float*)d_in[8];
  const float* Wec  = (const float*)d_in[9];
  const float* b2g  = (const float*)d_in[10];
  const float* b2b  = (const float*)d_in[11];
  const float* b2m  = (const float*)d_in[12];
  const float* b2v  = (const float*)d_in[13];
  const float* Wb   = (const float*)d_in[14];
  const float* bb   = (const float*)d_in[15];
  float* out = (float*)d_out;

  float* ws   = (float*)d_ws;
  float* pts  = ws;
  float* ptsT = pts + (size_t)NB*NPTS*NH;
  float* G1   = ptsT + (size_t)NB*NPTS*NH;
  float* G2   = G1  + (size_t)NB*NPTS*NH;
  float* x2   = G2  + (size_t)NB*NPTS*NH;
  float* sc1w = x2  + (size_t)NB*NPTS;
  int*   nidx = (int*)(sc1w + (size_t)NB*NPTS);

  hipLaunchKernelGGL(k_fc, dim3(NPTS/64, NB), dim3(256), 0, stream,
                     seq1, Wfc, bfc, b1g, b1b, b1m, b1v, Wec, pts, ptsT, G1, G2, x2);
  hipLaunchKernelGGL(k_knn, dim3(NB*NPTS/16), dim3(512), 0, stream,
                     pts, ptsT, x2, nidx);
  hipLaunchKernelGGL(k_score, dim3(NPTS/16, NB), dim3(256), 0, stream,
                     pts, G1, G2, nidx, perm, Wb, b2g, b2b, b2m, b2v, bb, sc1w, out);
  hipLaunchKernelGGL(k_select, dim3(NB), dim3(256), 0, stream,
                     sc1w, seq1, xyz, out);
}